// Round 8
// baseline (637.570 us; speedup 1.0000x reference)
//
#include <hip/hip_runtime.h>
#include <hip/hip_fp16.h>

#define N_NODES 100000
#define N_EDGES 1600000
#define D 128
#define BKT_SHIFT 9
#define BKT_N 512                    // nodes per bucket
#define NBKT 196                     // ceil(100000/512)
#define CAP 10240                    // per-bucket packed capacity (mean 8192, sigma~90)
#define NBLK_B 512                   // bucket-kernel blocks
#define EPB (N_EDGES / NBLK_B)       // 3125 edges/block
#define ZUINT4 ((2 * N_NODES + 128) / 4)  // zero region in uint4s
#define NSTRIPE 4                    // spmm column stripes (32 fp8 cols each)
#define NBW ((N_NODES + 3) / 4)      // spmm blocks per stripe (4 waves/block)

typedef _Float16 f16x4 __attribute__((ext_vector_type(4)));
typedef _Float16 f16x8 __attribute__((ext_vector_type(8)));
typedef float f32x4 __attribute__((ext_vector_type(4)));
typedef float f32x2 __attribute__((ext_vector_type(2)));

// ---------------------------------------------------------------------------
// Pass 0: Wt transpose (blocks [0,128)) + zero cnt_src/wsum/colsum + gcur init.
__global__ __launch_bounds__(256) void
k_zwt(const float* __restrict__ W0, const float* __restrict__ W1,
      __half* __restrict__ Wt, uint4* __restrict__ zbase,
      unsigned int* __restrict__ gcur) {
    if (blockIdx.x < 128) {
        int i = blockIdx.x * 256 + threadIdx.x;  // over 2*D*D
        int l = i >> 14, r = i & (D * D - 1);
        int n = r >> 7, k = r & 127;
        const float* W = l ? W1 : W0;
        Wt[i] = __float2half(W[k * D + n]);
        return;
    }
    if (blockIdx.x == 128 && threadIdx.x < NBKT)
        gcur[threadIdx.x] = (unsigned)threadIdx.x * CAP;
    int i = (blockIdx.x - 128) * 256 + threadIdx.x;
    if (i < ZUINT4) zbase[i] = (uint4){0u, 0u, 0u, 0u};
}

// Phase 1: bucket the edge list by dst>>9 into per-bucket windows.
// Packed word: (dst & 511) << 17 | src  (26 bits). Per-block LDS histogram
// reserves a contiguous window per bucket -> writes fill 64B lines densely.
// Fused: cnt_src[src]++ (out-degree).
__global__ __launch_bounds__(256) void
k_bucket(const int* __restrict__ src, const int* __restrict__ dst,
         unsigned int* __restrict__ gcur, unsigned int* __restrict__ packed,
         int* __restrict__ cnt_src) {
    __shared__ int hist[NBKT];
    __shared__ unsigned int base[NBKT];
    __shared__ int cur[NBKT];
    int tid = threadIdx.x;
    for (int i = tid; i < NBKT; i += 256) hist[i] = 0;
    __syncthreads();
    int e0 = blockIdx.x * EPB;
    for (int i = e0 + tid; i < e0 + EPB; i += 256)
        atomicAdd(&hist[dst[i] >> BKT_SHIFT], 1);
    __syncthreads();
    for (int i = tid; i < NBKT; i += 256) {
        base[i] = atomicAdd(&gcur[i], (unsigned)hist[i]);
        cur[i] = 0;
    }
    __syncthreads();
    for (int i = e0 + tid; i < e0 + EPB; i += 256) {
        int d = dst[i], s = src[i];
        int b = d >> BKT_SHIFT;
        int off = atomicAdd(&cur[b], 1);
        unsigned int pos = base[b] + (unsigned)off;
        if (pos < (unsigned)(b + 1) * CAP)  // 18-sigma guard, never taken
            packed[pos] = ((unsigned)(d & (BKT_N - 1)) << 17) | (unsigned)s;
        atomicAdd(&cnt_src[s], 1);
    }
}

// Tiny scan over 196 bucket sizes -> cbase (CSR base per bucket); rpD[N]=E.
__global__ __launch_bounds__(256) void
k_cscan(const unsigned int* __restrict__ gcur, int* __restrict__ cbase,
        int* __restrict__ rpD) {
    __shared__ int sc[2][256];
    int tid = threadIdx.x;
    int m = (tid < NBKT) ? (int)(gcur[tid] - (unsigned)tid * CAP) : 0;
    sc[0][tid] = m;
    int pb = 0;
    for (int d = 1; d < 256; d <<= 1) {
        __syncthreads();
        int v = sc[pb][tid];
        if (tid >= d) v += sc[pb][tid - d];
        sc[pb ^ 1][tid] = v;
        pb ^= 1;
    }
    __syncthreads();
    cbase[tid] = tid ? sc[pb][tid - 1] : 0;
    if (tid == 255) { cbase[256] = sc[pb][255]; rpD[N_NODES] = sc[pb][255]; }
}

// Phase 2: one block per bucket. Bucket region (L2-hot) read twice:
// LDS 512-counter histogram -> LDS prefix -> rpD/nd coalesced writes ->
// in-LDS scatter of src payloads -> fully coalesced csr_src streamout.
__global__ __launch_bounds__(256) void
k_csr(const unsigned int* __restrict__ gcur, const int* __restrict__ cbase,
      const unsigned int* __restrict__ packed, int* __restrict__ csr_src,
      int* __restrict__ rpD, float* __restrict__ nd) {
    __shared__ int cnt[BKT_N];
    __shared__ int sc[2][BKT_N];
    __shared__ int outb[CAP];
    int tid = threadIdx.x;
    int b = blockIdx.x;
    int m = (int)(gcur[b] - (unsigned)b * CAP);
    if (m > CAP) m = CAP;
    int base_in = b * CAP;
    int base_out = cbase[b];
    int n0 = b * BKT_N;
    for (int j = tid; j < BKT_N; j += 256) cnt[j] = 0;
    __syncthreads();
    for (int i = tid; i < m; i += 256)
        atomicAdd(&cnt[packed[base_in + i] >> 17], 1);
    __syncthreads();
    for (int j = tid; j < BKT_N; j += 256) sc[0][j] = cnt[j];
    int pb = 0;
    for (int d = 1; d < BKT_N; d <<= 1) {
        __syncthreads();
        for (int j = tid; j < BKT_N; j += 256) {
            int v = sc[pb][j];
            if (j >= d) v += sc[pb][j - d];
            sc[pb ^ 1][j] = v;
        }
        pb ^= 1;
    }
    __syncthreads();
    for (int j = tid; j < BKT_N; j += 256) {
        int excl = j ? sc[pb][j - 1] : 0;
        int n = n0 + j;
        if (n < N_NODES) {
            rpD[n] = base_out + excl;
            nd[n] = rsqrtf((float)max(cnt[j], 1));
        }
    }
    __syncthreads();
    for (int j = tid; j < BKT_N; j += 256)
        cnt[j] = j ? sc[pb][j - 1] : 0;  // reuse as scatter cursor
    __syncthreads();
    for (int i = tid; i < m; i += 256) {
        unsigned int p = packed[base_in + i];
        int din = p >> 17;
        int off = atomicAdd(&cnt[din], 1);
        outb[off] = (int)(p & 0x1FFFFu);
    }
    __syncthreads();
    for (int i = tid; i < m; i += 256)
        csr_src[base_out + i] = outb[i];
}

// x8[n][:] = fp8(h[n][:] * rsqrt(deg_out[n]))
__global__ void k_prep(const float* __restrict__ x, const int* __restrict__ cnt_src,
                       unsigned int* __restrict__ out) {
    int i = blockIdx.x * 256 + threadIdx.x;  // over N*D/4
    if (i >= N_NODES * (D / 4)) return;
    int n = i >> 5;
    float4 v = ((const float4*)x)[i];
    float s = rsqrtf((float)max(cnt_src[n], 1));
    int u = __builtin_amdgcn_cvt_pk_fp8_f32(v.x * s, v.y * s, 0, false);
    u = __builtin_amdgcn_cvt_pk_fp8_f32(v.z * s, v.w * s, u, true);
    out[i] = (unsigned int)u;
}

// Column-striped pull SpMM: 4 stripes of 32 fp8 cols. Per stripe the gather
// working set is N*32B = 3.2 MB -> L2-resident per XCD. Stripe = slow grid
// index so all CUs phase through stripes together. 8 lanes/edge, 8 edges
// per load instruction; 3-level shuffle reduce; lanes 0..7 store one 64B
// agg line. Fused wsum (stripe 0, one lane per edge).
__global__ __launch_bounds__(256) void
k_spmm(const unsigned char* __restrict__ x8, const int* __restrict__ row_ptr,
       const int* __restrict__ csr_src, __half* __restrict__ agg,
       const float* __restrict__ nd, float* __restrict__ wsum) {
    int stripe = blockIdx.x / NBW;
    int bin = blockIdx.x % NBW;
    int wave = bin * 4 + (threadIdx.x >> 6);
    int lane = threadIdx.x & 63;
    if (wave >= N_NODES) return;
    int eo = lane >> 3;          // edge slot 0..7
    int c4 = lane & 7;           // col-quad 0..7 within stripe
    int beg = row_ptr[wave], end = row_ptr[wave + 1];
    const unsigned char* xs = x8 + stripe * 32 + 4 * c4;
    bool do_w = (wsum != nullptr) && (stripe == 0);
    float ndr = do_w ? nd[wave] : 0.0f;
    float a0 = 0.f, a1 = 0.f, a2 = 0.f, a3 = 0.f;
    for (int j = beg; j < end; j += 8) {
        int idx = j + eo;
        if (idx < end) {
            int s = csr_src[idx];
            unsigned int u = *(const unsigned int*)(xs + (size_t)s * D);
            f32x2 lo = __builtin_amdgcn_cvt_pk_f32_fp8(u, false);
            f32x2 hi = __builtin_amdgcn_cvt_pk_f32_fp8(u, true);
            a0 += lo[0]; a1 += lo[1]; a2 += hi[0]; a3 += hi[1];
            if (do_w && c4 == 0) unsafeAtomicAdd(&wsum[s], ndr);
        }
    }
    a0 += __shfl_xor(a0, 8, 64);  a1 += __shfl_xor(a1, 8, 64);
    a2 += __shfl_xor(a2, 8, 64);  a3 += __shfl_xor(a3, 8, 64);
    a0 += __shfl_xor(a0, 16, 64); a1 += __shfl_xor(a1, 16, 64);
    a2 += __shfl_xor(a2, 16, 64); a3 += __shfl_xor(a3, 16, 64);
    a0 += __shfl_xor(a0, 32, 64); a1 += __shfl_xor(a1, 32, 64);
    a2 += __shfl_xor(a2, 32, 64); a3 += __shfl_xor(a3, 32, 64);
    if (eo == 0) {
        f16x4 o;
        o[0] = (_Float16)a0; o[1] = (_Float16)a1; o[2] = (_Float16)a2; o[3] = (_Float16)a3;
        ((f16x4*)(agg + (size_t)wave * D + stripe * 32))[c4] = o;
    }
}

// MFMA GEMM (layer 0): A fp16 (agg), out fp8 rows (pre-scaled by ns).
__global__ __launch_bounds__(256) void
k_gemm_mfma(const __half* __restrict__ A, const __half* __restrict__ Wt,
            const float* __restrict__ b, const float* __restrict__ nd,
            const int* __restrict__ cnt_src, unsigned char* __restrict__ out) {
    int w = threadIdx.x >> 6, lane = threadIdx.x & 63;
    int m = lane & 15, q = lane >> 4;
    int row0 = blockIdx.x * 128 + w * 32;

    f16x8 zf;
#pragma unroll
    for (int j = 0; j < 8; j++) zf[j] = (_Float16)0;
    f16x8 af[2][4];
#pragma unroll
    for (int g = 0; g < 2; g++) {
        int arow = row0 + g * 16 + m;
        const f16x8* pa = (const f16x8*)(A + (size_t)arow * D);
        bool aok = arow < N_NODES;
#pragma unroll
        for (int ks = 0; ks < 4; ks++) af[g][ks] = aok ? pa[ks * 4 + q] : zf;
    }

    const f16x8* pb = (const f16x8*)Wt;
    f32x4 acc[2][8];
#pragma unroll
    for (int g = 0; g < 2; g++)
#pragma unroll
        for (int nt = 0; nt < 8; nt++) acc[g][nt] = (f32x4){0.f, 0.f, 0.f, 0.f};

#pragma unroll
    for (int ks = 0; ks < 4; ks++) {
#pragma unroll
        for (int nt = 0; nt < 8; nt++) {
            f16x8 bf = pb[((nt * 16 + m) << 4) + (ks << 2) + q];
            acc[0][nt] = __builtin_amdgcn_mfma_f32_16x16x32_f16(af[0][ks], bf, acc[0][nt], 0, 0, 0);
            acc[1][nt] = __builtin_amdgcn_mfma_f32_16x16x32_f16(af[1][ks], bf, acc[1][nt], 0, 0, 0);
        }
    }

#pragma unroll
    for (int g = 0; g < 2; g++) {
        int er = row0 + g * 16 + q * 4;
        float sd[4], ss[4];
#pragma unroll
        for (int r = 0; r < 4; r++) {
            int n = er + r;
            bool ok = n < N_NODES;
            sd[r] = ok ? nd[n] : 0.0f;
            ss[r] = ok ? rsqrtf((float)max(cnt_src[n], 1)) : 0.0f;
        }
#pragma unroll
        for (int nt = 0; nt < 8; nt++) {
            int col = nt * 16 + m;
            float bc = b[col];
#pragma unroll
            for (int r = 0; r < 4; r++) {
                int n = er + r;
                if (n < N_NODES) {
                    float v = fmaxf(sd[r] * acc[g][nt][r] + bc, 0.0f) * ss[r];
                    int pk = __builtin_amdgcn_cvt_pk_fp8_f32(v, v, 0, false);
                    out[(size_t)n * D + col] = (unsigned char)(pk & 0xff);
                }
            }
        }
    }
}

// MFMA GEMM (layer 1 + fused final reduction):
// colsum[col] += sum_n ns[n]*wsum[n] * relu(nd[n]*(A@W1)[n][col] + b1[col])
__global__ __launch_bounds__(256) void
k_gemm_red(const __half* __restrict__ A, const __half* __restrict__ Wt,
           const float* __restrict__ b, const float* __restrict__ nd,
           const int* __restrict__ cnt_src, const float* __restrict__ wsum,
           float* __restrict__ colsum) {
    __shared__ float red[128];
    int tid = threadIdx.x;
    if (tid < 128) red[tid] = 0.0f;
    __syncthreads();

    int w = tid >> 6, lane = tid & 63;
    int m = lane & 15, q = lane >> 4;
    int row0 = blockIdx.x * 128 + w * 32;

    f16x8 zf;
#pragma unroll
    for (int j = 0; j < 8; j++) zf[j] = (_Float16)0;
    f16x8 af[2][4];
#pragma unroll
    for (int g = 0; g < 2; g++) {
        int arow = row0 + g * 16 + m;
        const f16x8* pa = (const f16x8*)(A + (size_t)arow * D);
        bool aok = arow < N_NODES;
#pragma unroll
        for (int ks = 0; ks < 4; ks++) af[g][ks] = aok ? pa[ks * 4 + q] : zf;
    }

    const f16x8* pb = (const f16x8*)Wt;
    f32x4 acc[2][8];
#pragma unroll
    for (int g = 0; g < 2; g++)
#pragma unroll
        for (int nt = 0; nt < 8; nt++) acc[g][nt] = (f32x4){0.f, 0.f, 0.f, 0.f};

#pragma unroll
    for (int ks = 0; ks < 4; ks++) {
#pragma unroll
        for (int nt = 0; nt < 8; nt++) {
            f16x8 bf = pb[((nt * 16 + m) << 4) + (ks << 2) + q];
            acc[0][nt] = __builtin_amdgcn_mfma_f32_16x16x32_f16(af[0][ks], bf, acc[0][nt], 0, 0, 0);
            acc[1][nt] = __builtin_amdgcn_mfma_f32_16x16x32_f16(af[1][ks], bf, acc[1][nt], 0, 0, 0);
        }
    }

    float sd[2][4], sw[2][4];
#pragma unroll
    for (int g = 0; g < 2; g++) {
        int er = row0 + g * 16 + q * 4;
#pragma unroll
        for (int r = 0; r < 4; r++) {
            int n = er + r;
            bool ok = n < N_NODES;
            sd[g][r] = ok ? nd[n] : 0.0f;
            sw[g][r] = ok ? wsum[n] * rsqrtf((float)max(cnt_src[n], 1)) : 0.0f;
        }
    }
#pragma unroll
    for (int nt = 0; nt < 8; nt++) {
        int col = nt * 16 + m;
        float bc = b[col];
        float pc = 0.0f;
#pragma unroll
        for (int g = 0; g < 2; g++)
#pragma unroll
            for (int r = 0; r < 4; r++)
                pc += sw[g][r] * fmaxf(sd[g][r] * acc[g][nt][r] + bc, 0.0f);
        atomicAdd(&red[col], pc);
    }
    __syncthreads();
    if (tid < 128) unsafeAtomicAdd(&colsum[tid], red[tid]);
}

// out[j] = (colsum/N) @ W2 [:,j] + b2[j]
__global__ void k_final(const float* __restrict__ colsum, const float* __restrict__ W,
                        const float* __restrict__ b, float* __restrict__ out) {
    __shared__ float m[128];
    int j = threadIdx.x;
    m[j] = colsum[j] * (1.0f / N_NODES);
    __syncthreads();
    float acc = b[j];
    for (int k = 0; k < 128; k++)
        acc = fmaf(m[k], W[(size_t)k * D + j], acc);
    out[j] = acc;
}

extern "C" void kernel_launch(void* const* d_in, const int* in_sizes, int n_in,
                              void* d_out, int out_size, void* d_ws, size_t ws_size,
                              hipStream_t stream) {
    const float* h   = (const float*)d_in[0];
    const int*   src = (const int*)d_in[1];
    const int*   dst = (const int*)d_in[2];
    const float* W0  = (const float*)d_in[3];
    const float* b0  = (const float*)d_in[4];
    const float* W1  = (const float*)d_in[5];
    const float* b1  = (const float*)d_in[6];
    const float* W2  = (const float*)d_in[7];
    const float* b2  = (const float*)d_in[8];
    float* out = (float*)d_out;

    // workspace (~47 MB). [cnt_src|wsum|colsum] = zero region.
    int*           cnt_src = (int*)d_ws;                          // N (zeroed)
    float*         wsum    = (float*)(cnt_src + N_NODES);         // N (zeroed)
    float*         colsum  = wsum + N_NODES;                      // 128 (zeroed)
    float*         nd      = colsum + 128;                        // N
    int*           rpD     = (int*)(nd + N_NODES);                // N+1 (+3 pad)
    unsigned int*  gcur    = (unsigned int*)(rpD + N_NODES + 4);  // 256
    int*           cbase   = (int*)(gcur + 256);                  // 257 (+3 pad)
    __half*        Wt16    = (__half*)(cbase + 260);              // 2*D*D halves
    int*           csr_src = (int*)(Wt16 + 2 * D * D);            // E
    unsigned int*  packed  = (unsigned int*)(csr_src + N_EDGES);  // NBKT*CAP (8 MB)
    unsigned char* x8      = (unsigned char*)packed;              // N*D fp8 (12.8 MB, aliases packed)
    __half*        agg16   = (__half*)(x8 + (size_t)N_NODES * D); // N*D fp16

    // ---- CSR build via two-phase bucket sort ----
    k_zwt<<<128 + (ZUINT4 + 255) / 256, 256, 0, stream>>>(
        W0, W1, Wt16, (uint4*)d_ws, gcur);
    k_bucket<<<NBLK_B, 256, 0, stream>>>(src, dst, gcur, packed, cnt_src);
    k_cscan<<<1, 256, 0, stream>>>(gcur, cbase, rpD);
    k_csr<<<NBKT, 256, 0, stream>>>(gcur, cbase, packed, csr_src, rpD, nd);

    // x0 = fp8(h*ns)  (x8 overwrites packed — stream-ordered after k_csr)
    k_prep<<<(N_NODES * (D / 4) + 255) / 256, 256, 0, stream>>>(h, cnt_src,
                                                                (unsigned int*)x8);

    // layer 0
    k_spmm<<<NSTRIPE * NBW, 256, 0, stream>>>(x8, rpD, csr_src, agg16,
                                              nd, (float*)nullptr);
    k_gemm_mfma<<<(N_NODES + 127) / 128, 256, 0, stream>>>(agg16, Wt16, b0, nd,
                                                           cnt_src, x8);
    // layer 1 (+ fused wsum) + fused layer-2 reduction
    k_spmm<<<NSTRIPE * NBW, 256, 0, stream>>>(x8, rpD, csr_src, agg16,
                                              nd, wsum);
    k_gemm_red<<<(N_NODES + 127) / 128, 256, 0, stream>>>(agg16, Wt16 + (size_t)D * D,
                                                          b1, nd, cnt_src, wsum, colsum);
    k_final<<<1, 128, 0, stream>>>(colsum, W2, b2, out);
}

// Round 9
// 467.774 us; speedup vs baseline: 1.3630x; 1.3630x over previous
//
#include <hip/hip_runtime.h>
#include <hip/hip_fp16.h>

#define N_NODES 100000
#define N_EDGES 1600000
#define D 128
#define BKT_SHIFT 9
#define BKT_N 512                    // nodes per bucket
#define NBKT 196                     // ceil(100000/512)
#define CAP 10240                    // per-bucket packed capacity (mean 8192, sigma~90)
#define NBLK_B 625                   // bucket-kernel blocks
#define EPT 10                       // edges per thread (625*256*10 = 1.6M exactly)
#define EPB (256 * EPT)              // 2560 edges/block
#define ZUINT4 ((2 * N_NODES + 128) / 4)  // zero region in uint4s

typedef _Float16 f16x4 __attribute__((ext_vector_type(4)));
typedef _Float16 f16x8 __attribute__((ext_vector_type(8)));
typedef float f32x4 __attribute__((ext_vector_type(4)));
typedef float f32x2 __attribute__((ext_vector_type(2)));

// ---------------------------------------------------------------------------
// Pass 0: Wt transpose (blocks [0,128)) + zero cnt_src/wsum/colsum + gcur init.
__global__ __launch_bounds__(256) void
k_zwt(const float* __restrict__ W0, const float* __restrict__ W1,
      __half* __restrict__ Wt, uint4* __restrict__ zbase,
      unsigned int* __restrict__ gcur) {
    if (blockIdx.x < 128) {
        int i = blockIdx.x * 256 + threadIdx.x;  // over 2*D*D
        int l = i >> 14, r = i & (D * D - 1);
        int n = r >> 7, k = r & 127;
        const float* W = l ? W1 : W0;
        Wt[i] = __float2half(W[k * D + n]);
        return;
    }
    if (blockIdx.x == 128 && threadIdx.x < NBKT)
        gcur[threadIdx.x] = (unsigned)threadIdx.x * CAP;
    int i = (blockIdx.x - 128) * 256 + threadIdx.x;
    if (i < ZUINT4) zbase[i] = (uint4){0u, 0u, 0u, 0u};
}

// Phase 1: bucket edges by dst>>9 into per-bucket windows. Single pass over
// the edge list: dst/src held in fully-unrolled register arrays (static
// indices) across histogram -> reserve -> write. Packed word:
// (dst & 511) << 17 | src. Fused: cnt_src[src]++ (out-degree).
__global__ __launch_bounds__(256) void
k_bucket(const int* __restrict__ src, const int* __restrict__ dst,
         unsigned int* __restrict__ gcur, unsigned int* __restrict__ packed,
         int* __restrict__ cnt_src) {
    __shared__ int hist[NBKT];
    __shared__ unsigned int base[NBKT];
    __shared__ int cur[NBKT];
    int tid = threadIdx.x;
    for (int i = tid; i < NBKT; i += 256) hist[i] = 0;
    __syncthreads();
    int e0 = blockIdx.x * EPB + tid;
    int dloc[EPT], sloc[EPT];
#pragma unroll
    for (int k = 0; k < EPT; k++) {
        int d = dst[e0 + k * 256];
        int s = src[e0 + k * 256];
        dloc[k] = d; sloc[k] = s;
        atomicAdd(&hist[d >> BKT_SHIFT], 1);
        atomicAdd(&cnt_src[s], 1);
    }
    __syncthreads();
    for (int i = tid; i < NBKT; i += 256) {
        base[i] = atomicAdd(&gcur[i], (unsigned)hist[i]);
        cur[i] = 0;
    }
    __syncthreads();
#pragma unroll
    for (int k = 0; k < EPT; k++) {
        int d = dloc[k], s = sloc[k];
        int b = d >> BKT_SHIFT;
        int off = atomicAdd(&cur[b], 1);
        unsigned int pos = base[b] + (unsigned)off;
        if (pos < (unsigned)(b + 1) * CAP)  // overflow guard, never taken
            packed[pos] = ((unsigned)(d & (BKT_N - 1)) << 17) | (unsigned)s;
    }
}

// Tiny scan over 196 bucket sizes -> cbase (CSR base per bucket); rpD[N]=E.
__global__ __launch_bounds__(256) void
k_cscan(const unsigned int* __restrict__ gcur, int* __restrict__ cbase,
        int* __restrict__ rpD) {
    __shared__ int sc[2][256];
    int tid = threadIdx.x;
    int m = (tid < NBKT) ? (int)(gcur[tid] - (unsigned)tid * CAP) : 0;
    sc[0][tid] = m;
    int pb = 0;
    for (int d = 1; d < 256; d <<= 1) {
        __syncthreads();
        int v = sc[pb][tid];
        if (tid >= d) v += sc[pb][tid - d];
        sc[pb ^ 1][tid] = v;
        pb ^= 1;
    }
    __syncthreads();
    cbase[tid] = tid ? sc[pb][tid - 1] : 0;
    if (tid == 255) { cbase[256] = sc[pb][255]; rpD[N_NODES] = sc[pb][255]; }
}

// Phase 2: one block (512 threads) per bucket, one node per thread.
// LDS 512-counter histogram -> prefix -> rpD/nd coalesced writes ->
// DIRECT global scatter into the bucket's ~33 KB csr_src window (L2-local).
// LDS only 6 KB (no staging buffer).
__global__ __launch_bounds__(512) void
k_csr(const unsigned int* __restrict__ gcur, const int* __restrict__ cbase,
      const unsigned int* __restrict__ packed, int* __restrict__ csr_src,
      int* __restrict__ rpD, float* __restrict__ nd) {
    __shared__ int cnt[BKT_N];
    __shared__ int sc[2][BKT_N];
    __shared__ int cur[BKT_N];
    int tid = threadIdx.x;
    int b = blockIdx.x;
    int m = (int)(gcur[b] - (unsigned)b * CAP);
    if (m > CAP) m = CAP;
    int base_in = b * CAP;
    int base_out = cbase[b];
    int n0 = b * BKT_N;
    cnt[tid] = 0;
    __syncthreads();
    for (int i = tid; i < m; i += 512)
        atomicAdd(&cnt[packed[base_in + i] >> 17], 1);
    __syncthreads();
    int v = cnt[tid];
    sc[0][tid] = v;
    int pb = 0;
    for (int d = 1; d < BKT_N; d <<= 1) {
        __syncthreads();
        int t = sc[pb][tid];
        if (tid >= d) t += sc[pb][tid - d];
        sc[pb ^ 1][tid] = t;
        pb ^= 1;
    }
    __syncthreads();
    int excl = sc[pb][tid] - v;  // exclusive prefix
    int n = n0 + tid;
    if (n < N_NODES) {
        rpD[n] = base_out + excl;
        nd[n] = rsqrtf((float)max(v, 1));
    }
    cur[tid] = excl;
    __syncthreads();
    for (int i = tid; i < m; i += 512) {
        unsigned int p = packed[base_in + i];
        int din = p >> 17;
        int off = atomicAdd(&cur[din], 1);
        csr_src[base_out + off] = (int)(p & 0x1FFFFu);
    }
}

// x8[n][:] = fp8(h[n][:] * rsqrt(deg_out[n]))
__global__ void k_prep(const float* __restrict__ x, const int* __restrict__ cnt_src,
                       unsigned int* __restrict__ out) {
    int i = blockIdx.x * 256 + threadIdx.x;  // over N*D/4
    if (i >= N_NODES * (D / 4)) return;
    int n = i >> 5;
    float4 v = ((const float4*)x)[i];
    float s = rsqrtf((float)max(cnt_src[n], 1));
    int u = __builtin_amdgcn_cvt_pk_fp8_f32(v.x * s, v.y * s, 0, false);
    u = __builtin_amdgcn_cvt_pk_fp8_f32(v.z * s, v.w * s, u, true);
    out[i] = (unsigned int)u;
}

// pull SpMM (fp8 gather -> fp32 accum -> fp16 agg): one wave per node,
// 2 edges per gather instruction (lane reads uint = 4 fp8; 32 lanes/row).
// Optional fused wsum: wsum[src] += nd[row] (one lane per edge).
__global__ __launch_bounds__(256) void
k_spmm(const unsigned char* __restrict__ x8, const int* __restrict__ row_ptr,
       const int* __restrict__ csr_src, __half* __restrict__ agg,
       const float* __restrict__ nd, float* __restrict__ wsum) {
    int wave = (blockIdx.x * blockDim.x + threadIdx.x) >> 6;
    int lane = threadIdx.x & 63;
    int hf = lane >> 5, l32 = lane & 31;
    if (wave >= N_NODES) return;
    int beg = row_ptr[wave], end = row_ptr[wave + 1];
    float ndr = wsum ? nd[wave] : 0.0f;
    float a0 = 0.f, a1 = 0.f, a2 = 0.f, a3 = 0.f;
    int j = beg;
    for (; j + 7 < end; j += 8) {
#pragma unroll
        for (int p = 0; p < 4; p++) {
            int s0 = csr_src[j + 2 * p];
            int s1 = csr_src[j + 2 * p + 1];
            int s = hf ? s1 : s0;
            unsigned int u = *(const unsigned int*)(x8 + (size_t)s * D + 4 * l32);
            f32x2 lo = __builtin_amdgcn_cvt_pk_f32_fp8(u, false);
            f32x2 hi = __builtin_amdgcn_cvt_pk_f32_fp8(u, true);
            a0 += lo[0]; a1 += lo[1]; a2 += hi[0]; a3 += hi[1];
            if (wsum && l32 == 0) unsafeAtomicAdd(&wsum[s], ndr);
        }
    }
    for (; j + 1 < end; j += 2) {
        int s0 = csr_src[j], s1 = csr_src[j + 1];
        int s = hf ? s1 : s0;
        unsigned int u = *(const unsigned int*)(x8 + (size_t)s * D + 4 * l32);
        f32x2 lo = __builtin_amdgcn_cvt_pk_f32_fp8(u, false);
        f32x2 hi = __builtin_amdgcn_cvt_pk_f32_fp8(u, true);
        a0 += lo[0]; a1 += lo[1]; a2 += hi[0]; a3 += hi[1];
        if (wsum && l32 == 0) unsafeAtomicAdd(&wsum[s], ndr);
    }
    if (j < end && hf == 0) {
        int s = csr_src[j];
        unsigned int u = *(const unsigned int*)(x8 + (size_t)s * D + 4 * l32);
        f32x2 lo = __builtin_amdgcn_cvt_pk_f32_fp8(u, false);
        f32x2 hi = __builtin_amdgcn_cvt_pk_f32_fp8(u, true);
        a0 += lo[0]; a1 += lo[1]; a2 += hi[0]; a3 += hi[1];
        if (wsum && l32 == 0) unsafeAtomicAdd(&wsum[s], ndr);
    }
    a0 += __shfl_xor(a0, 32, 64);
    a1 += __shfl_xor(a1, 32, 64);
    a2 += __shfl_xor(a2, 32, 64);
    a3 += __shfl_xor(a3, 32, 64);
    if (hf == 0) {
        f16x4 o;
        o[0] = (_Float16)a0; o[1] = (_Float16)a1; o[2] = (_Float16)a2; o[3] = (_Float16)a3;
        ((f16x4*)(agg + (size_t)wave * D))[l32] = o;
    }
}

// MFMA GEMM (layer 0): A fp16 (agg), out fp8 rows (pre-scaled by ns).
__global__ __launch_bounds__(256) void
k_gemm_mfma(const __half* __restrict__ A, const __half* __restrict__ Wt,
            const float* __restrict__ b, const float* __restrict__ nd,
            const int* __restrict__ cnt_src, unsigned char* __restrict__ out) {
    int w = threadIdx.x >> 6, lane = threadIdx.x & 63;
    int m = lane & 15, q = lane >> 4;
    int row0 = blockIdx.x * 128 + w * 32;

    f16x8 zf;
#pragma unroll
    for (int j = 0; j < 8; j++) zf[j] = (_Float16)0;
    f16x8 af[2][4];
#pragma unroll
    for (int g = 0; g < 2; g++) {
        int arow = row0 + g * 16 + m;
        const f16x8* pa = (const f16x8*)(A + (size_t)arow * D);
        bool aok = arow < N_NODES;
#pragma unroll
        for (int ks = 0; ks < 4; ks++) af[g][ks] = aok ? pa[ks * 4 + q] : zf;
    }

    const f16x8* pb = (const f16x8*)Wt;
    f32x4 acc[2][8];
#pragma unroll
    for (int g = 0; g < 2; g++)
#pragma unroll
        for (int nt = 0; nt < 8; nt++) acc[g][nt] = (f32x4){0.f, 0.f, 0.f, 0.f};

#pragma unroll
    for (int ks = 0; ks < 4; ks++) {
#pragma unroll
        for (int nt = 0; nt < 8; nt++) {
            f16x8 bf = pb[((nt * 16 + m) << 4) + (ks << 2) + q];
            acc[0][nt] = __builtin_amdgcn_mfma_f32_16x16x32_f16(af[0][ks], bf, acc[0][nt], 0, 0, 0);
            acc[1][nt] = __builtin_amdgcn_mfma_f32_16x16x32_f16(af[1][ks], bf, acc[1][nt], 0, 0, 0);
        }
    }

#pragma unroll
    for (int g = 0; g < 2; g++) {
        int er = row0 + g * 16 + q * 4;
        float sd[4], ss[4];
#pragma unroll
        for (int r = 0; r < 4; r++) {
            int n = er + r;
            bool ok = n < N_NODES;
            sd[r] = ok ? nd[n] : 0.0f;
            ss[r] = ok ? rsqrtf((float)max(cnt_src[n], 1)) : 0.0f;
        }
#pragma unroll
        for (int nt = 0; nt < 8; nt++) {
            int col = nt * 16 + m;
            float bc = b[col];
#pragma unroll
            for (int r = 0; r < 4; r++) {
                int n = er + r;
                if (n < N_NODES) {
                    float v = fmaxf(sd[r] * acc[g][nt][r] + bc, 0.0f) * ss[r];
                    int pk = __builtin_amdgcn_cvt_pk_fp8_f32(v, v, 0, false);
                    out[(size_t)n * D + col] = (unsigned char)(pk & 0xff);
                }
            }
        }
    }
}

// MFMA GEMM (layer 1 + fused final reduction):
// colsum[col] += sum_n ns[n]*wsum[n] * relu(nd[n]*(A@W1)[n][col] + b1[col])
__global__ __launch_bounds__(256) void
k_gemm_red(const __half* __restrict__ A, const __half* __restrict__ Wt,
           const float* __restrict__ b, const float* __restrict__ nd,
           const int* __restrict__ cnt_src, const float* __restrict__ wsum,
           float* __restrict__ colsum) {
    __shared__ float red[128];
    int tid = threadIdx.x;
    if (tid < 128) red[tid] = 0.0f;
    __syncthreads();

    int w = tid >> 6, lane = tid & 63;
    int m = lane & 15, q = lane >> 4;
    int row0 = blockIdx.x * 128 + w * 32;

    f16x8 zf;
#pragma unroll
    for (int j = 0; j < 8; j++) zf[j] = (_Float16)0;
    f16x8 af[2][4];
#pragma unroll
    for (int g = 0; g < 2; g++) {
        int arow = row0 + g * 16 + m;
        const f16x8* pa = (const f16x8*)(A + (size_t)arow * D);
        bool aok = arow < N_NODES;
#pragma unroll
        for (int ks = 0; ks < 4; ks++) af[g][ks] = aok ? pa[ks * 4 + q] : zf;
    }

    const f16x8* pb = (const f16x8*)Wt;
    f32x4 acc[2][8];
#pragma unroll
    for (int g = 0; g < 2; g++)
#pragma unroll
        for (int nt = 0; nt < 8; nt++) acc[g][nt] = (f32x4){0.f, 0.f, 0.f, 0.f};

#pragma unroll
    for (int ks = 0; ks < 4; ks++) {
#pragma unroll
        for (int nt = 0; nt < 8; nt++) {
            f16x8 bf = pb[((nt * 16 + m) << 4) + (ks << 2) + q];
            acc[0][nt] = __builtin_amdgcn_mfma_f32_16x16x32_f16(af[0][ks], bf, acc[0][nt], 0, 0, 0);
            acc[1][nt] = __builtin_amdgcn_mfma_f32_16x16x32_f16(af[1][ks], bf, acc[1][nt], 0, 0, 0);
        }
    }

    float sd[2][4], sw[2][4];
#pragma unroll
    for (int g = 0; g < 2; g++) {
        int er = row0 + g * 16 + q * 4;
#pragma unroll
        for (int r = 0; r < 4; r++) {
            int n = er + r;
            bool ok = n < N_NODES;
            sd[g][r] = ok ? nd[n] : 0.0f;
            sw[g][r] = ok ? wsum[n] * rsqrtf((float)max(cnt_src[n], 1)) : 0.0f;
        }
    }
#pragma unroll
    for (int nt = 0; nt < 8; nt++) {
        int col = nt * 16 + m;
        float bc = b[col];
        float pc = 0.0f;
#pragma unroll
        for (int g = 0; g < 2; g++)
#pragma unroll
            for (int r = 0; r < 4; r++)
                pc += sw[g][r] * fmaxf(sd[g][r] * acc[g][nt][r] + bc, 0.0f);
        atomicAdd(&red[col], pc);
    }
    __syncthreads();
    if (tid < 128) unsafeAtomicAdd(&colsum[tid], red[tid]);
}

// out[j] = (colsum/N) @ W2 [:,j] + b2[j]
__global__ void k_final(const float* __restrict__ colsum, const float* __restrict__ W,
                        const float* __restrict__ b, float* __restrict__ out) {
    __shared__ float m[128];
    int j = threadIdx.x;
    m[j] = colsum[j] * (1.0f / N_NODES);
    __syncthreads();
    float acc = b[j];
    for (int k = 0; k < 128; k++)
        acc = fmaf(m[k], W[(size_t)k * D + j], acc);
    out[j] = acc;
}

extern "C" void kernel_launch(void* const* d_in, const int* in_sizes, int n_in,
                              void* d_out, int out_size, void* d_ws, size_t ws_size,
                              hipStream_t stream) {
    const float* h   = (const float*)d_in[0];
    const int*   src = (const int*)d_in[1];
    const int*   dst = (const int*)d_in[2];
    const float* W0  = (const float*)d_in[3];
    const float* b0  = (const float*)d_in[4];
    const float* W1  = (const float*)d_in[5];
    const float* b1  = (const float*)d_in[6];
    const float* W2  = (const float*)d_in[7];
    const float* b2  = (const float*)d_in[8];
    float* out = (float*)d_out;

    // workspace (~47 MB). [cnt_src|wsum|colsum] = zero region.
    int*           cnt_src = (int*)d_ws;                          // N (zeroed)
    float*         wsum    = (float*)(cnt_src + N_NODES);         // N (zeroed)
    float*         colsum  = wsum + N_NODES;                      // 128 (zeroed)
    float*         nd      = colsum + 128;                        // N
    int*           rpD     = (int*)(nd + N_NODES);                // N+1 (+3 pad)
    unsigned int*  gcur    = (unsigned int*)(rpD + N_NODES + 4);  // 256
    int*           cbase   = (int*)(gcur + 256);                  // 257 (+3 pad)
    __half*        Wt16    = (__half*)(cbase + 260);              // 2*D*D halves
    int*           csr_src = (int*)(Wt16 + 2 * D * D);            // E
    unsigned int*  packed  = (unsigned int*)(csr_src + N_EDGES);  // NBKT*CAP (8 MB)
    unsigned char* x8      = (unsigned char*)packed;              // N*D fp8 (12.8 MB, aliases packed)
    __half*        agg16   = (__half*)(x8 + (size_t)N_NODES * D); // N*D fp16

    // ---- CSR build via two-phase bucket sort ----
    k_zwt<<<128 + (ZUINT4 + 255) / 256, 256, 0, stream>>>(
        W0, W1, Wt16, (uint4*)d_ws, gcur);
    k_bucket<<<NBLK_B, 256, 0, stream>>>(src, dst, gcur, packed, cnt_src);
    k_cscan<<<1, 256, 0, stream>>>(gcur, cbase, rpD);
    k_csr<<<NBKT, 512, 0, stream>>>(gcur, cbase, packed, csr_src, rpD, nd);

    // x0 = fp8(h*ns)  (x8 overwrites packed — stream-ordered after k_csr)
    k_prep<<<(N_NODES * (D / 4) + 255) / 256, 256, 0, stream>>>(h, cnt_src,
                                                                (unsigned int*)x8);

    // layer 0
    k_spmm<<<(N_NODES + 3) / 4, 256, 0, stream>>>(x8, rpD, csr_src, agg16,
                                                  nd, (float*)nullptr);
    k_gemm_mfma<<<(N_NODES + 127) / 128, 256, 0, stream>>>(agg16, Wt16, b0, nd,
                                                           cnt_src, x8);
    // layer 1 (+ fused wsum) + fused layer-2 reduction
    k_spmm<<<(N_NODES + 3) / 4, 256, 0, stream>>>(x8, rpD, csr_src, agg16,
                                                  nd, wsum);
    k_gemm_red<<<(N_NODES + 127) / 128, 256, 0, stream>>>(agg16, Wt16 + (size_t)D * D,
                                                          b1, nd, cnt_src, wsum, colsum);
    k_final<<<1, 128, 0, stream>>>(colsum, W2, b2, out);
}